// Round 1
// baseline (760.802 us; speedup 1.0000x reference)
//
#include <hip/hip_runtime.h>
#include <hip/hip_bf16.h>

// SDPA with materialized attention output.
// B=2 H=16 S=2048 D=64. d_out = [context (B,H,S,D) | attention (B,H,S,S)], fp32.
// Two-sweep safe-softmax-without-max (scores are O(6), exp never overflows; masked
// entries -> exp(-1e9)=0 exactly, matching the reference bit-for-bit at p=0).
//
// Per workgroup (512 thr = 8 waves): 128 q-rows (16 per wave), iterate 32 k-tiles of 64.
// Sweep 1: QK^T (mfma 16x16x32 bf16, Q pre-scaled by 0.125) + exp -> row-sums l (regs).
// Sweep 2: recompute QK^T, write attn = p/l (nontemporal), P->LDS (bf16), PV mfma.

#define S_LEN 2048
#define D_DIM 64
#define LOG2E 1.44269504088896340736f

typedef __attribute__((ext_vector_type(8))) short bf16x8;
typedef __attribute__((ext_vector_type(4))) float f32x4;

__device__ __forceinline__ short f2bs(float f) {
    union { __hip_bfloat16 h; short s; } u;
    u.h = __float2bfloat16(f);
    return u.s;
}

__device__ __forceinline__ unsigned int f2bs2(float x, float y) {
    float2 t = make_float2(x, y);
    union { __hip_bfloat162 h; unsigned int u; } u;
    u.h = __float22bfloat162_rn(t);
    return u.u;
}

__device__ __forceinline__ bf16x8 cvt8(float4 a, float4 b) {
    union { bf16x8 v; unsigned int w[4]; } u;
    u.w[0] = f2bs2(a.x, a.y);
    u.w[1] = f2bs2(a.z, a.w);
    u.w[2] = f2bs2(b.x, b.y);
    u.w[3] = f2bs2(b.z, b.w);
    return u.v;
}

__global__ __launch_bounds__(512, 4) void sdpa_kernel(
    const float* __restrict__ Q, const float* __restrict__ K,
    const float* __restrict__ V, const int* __restrict__ Mask,
    float* __restrict__ Ctx, float* __restrict__ Attn)
{
    // LDS: K-tile row-major [key][d] stride 72 (2-way bank conflicts only = free),
    // V-tile TRANSPOSED [d][key] stride 72 (so PV B-frags are contiguous b128),
    // P per-wave [16][72] for the C-layout -> A-layout round trip.
    __shared__ __attribute__((aligned(16))) short Kt[64 * 72];
    __shared__ __attribute__((aligned(16))) short Vt[64 * 72];
    __shared__ __attribute__((aligned(16))) short Pt[8 * 16 * 72];

    const int tid  = threadIdx.x;
    const int wave = tid >> 6;
    const int lane = tid & 63;
    const int quad = lane >> 4;
    const int l16  = lane & 15;

    const int bid = blockIdx.x;   // 512 blocks: 32 (b,h) x 16 q-tiles
    const int bh  = bid >> 4;
    const int qt  = bid & 15;
    const int b   = bh >> 4;      // H = 16

    const size_t sd_off = (size_t)bh * S_LEN * D_DIM;
    const float* Qbh = Q + sd_off;
    const float* Kbh = K + sd_off;
    const float* Vbh = V + sd_off;
    const int*   Mb  = Mask + (size_t)b * S_LEN * S_LEN;   // mask broadcast over H
    float* Cbh = Ctx + sd_off;
    float* Abh = Attn + (size_t)bh * S_LEN * S_LEN;

    const int qw = qt * 128 + wave * 16;   // this wave's q-row base

    // ---- Q fragments (A-operand), pre-scaled by 1/sqrt(64) = 0.125 (exact) ----
    bf16x8 qfrag[2];
    {
        const int qrow = qw + l16;         // A: m = lane&15
        #pragma unroll
        for (int kc = 0; kc < 2; ++kc) {   // A: k = kc*32 + quad*8 + j
            const float* qp = Qbh + (size_t)qrow * D_DIM + kc * 32 + quad * 8;
            float4 a = *(const float4*)qp;
            float4 c = *(const float4*)(qp + 4);
            a.x *= 0.125f; a.y *= 0.125f; a.z *= 0.125f; a.w *= 0.125f;
            c.x *= 0.125f; c.y *= 0.125f; c.z *= 0.125f; c.w *= 0.125f;
            qfrag[kc] = cvt8(a, c);
        }
    }

    // staging assignment: thread -> (key row, 8-float d chunk); coalesced global reads
    const int skey = tid >> 3;
    const int sd   = (tid & 7) * 8;

    // ================= sweep 1: row sums l =================
    float lacc[4] = {0.f, 0.f, 0.f, 0.f};

    for (int kt = 0; kt < 32; ++kt) {
        const int k0 = kt * 64;
        __syncthreads();
        {
            const float* kp = Kbh + (size_t)(k0 + skey) * D_DIM + sd;
            float4 a = *(const float4*)kp;
            float4 c = *(const float4*)(kp + 4);
            *(bf16x8*)&Kt[skey * 72 + sd] = cvt8(a, c);
        }
        __syncthreads();

        #pragma unroll
        for (int cc = 0; cc < 4; ++cc) {
            f32x4 acc = {0.f, 0.f, 0.f, 0.f};
            const int keyl = cc * 16 + l16;               // B: n = lane&15
            bf16x8 b0 = *(const bf16x8*)&Kt[keyl * 72 + quad * 8];
            bf16x8 b1 = *(const bf16x8*)&Kt[keyl * 72 + 32 + quad * 8];
            acc = __builtin_amdgcn_mfma_f32_16x16x32_bf16(qfrag[0], b0, acc, 0, 0, 0);
            acc = __builtin_amdgcn_mfma_f32_16x16x32_bf16(qfrag[1], b1, acc, 0, 0, 0);
            // D: row = qw + quad*4 + r, col = k0 + keyl
            const int col = k0 + keyl;
            const int* mp = Mb + (size_t)(qw + quad * 4) * S_LEN + col;
            #pragma unroll
            for (int r = 0; r < 4; ++r) {
                int m = mp[(size_t)r * S_LEN];
                float p = m ? 0.f : exp2f(acc[r] * LOG2E);
                lacc[r] += p;
            }
        }
    }

    // reduce over the 16 lanes of each quad (cols) -> every lane holds row sums
    #pragma unroll
    for (int off = 1; off < 16; off <<= 1) {
        #pragma unroll
        for (int r = 0; r < 4; ++r)
            lacc[r] += __shfl_xor(lacc[r], off, 64);
    }
    float inv_l[4];
    #pragma unroll
    for (int r = 0; r < 4; ++r) inv_l[r] = 1.0f / lacc[r];

    // ================= sweep 2: attn write + PV =================
    f32x4 cacc[4];
    #pragma unroll
    for (int dc = 0; dc < 4; ++dc) cacc[dc] = (f32x4){0.f, 0.f, 0.f, 0.f};
    short* Pw = &Pt[wave * 16 * 72];

    for (int kt = 0; kt < 32; ++kt) {
        const int k0 = kt * 64;
        __syncthreads();
        {
            const float* kp = Kbh + (size_t)(k0 + skey) * D_DIM + sd;
            float4 a = *(const float4*)kp;
            float4 c = *(const float4*)(kp + 4);
            *(bf16x8*)&Kt[skey * 72 + sd] = cvt8(a, c);
            const float* vp = Vbh + (size_t)(k0 + skey) * D_DIM + sd;
            float4 va = *(const float4*)vp;
            float4 vb = *(const float4*)(vp + 4);
            float vv[8] = {va.x, va.y, va.z, va.w, vb.x, vb.y, vb.z, vb.w};
            #pragma unroll
            for (int i = 0; i < 8; ++i)                    // transposed store
                Vt[(sd + i) * 72 + skey] = f2bs(vv[i]);
        }
        __syncthreads();

        #pragma unroll
        for (int cc = 0; cc < 4; ++cc) {
            f32x4 acc = {0.f, 0.f, 0.f, 0.f};
            const int keyl = cc * 16 + l16;
            bf16x8 b0 = *(const bf16x8*)&Kt[keyl * 72 + quad * 8];
            bf16x8 b1 = *(const bf16x8*)&Kt[keyl * 72 + 32 + quad * 8];
            acc = __builtin_amdgcn_mfma_f32_16x16x32_bf16(qfrag[0], b0, acc, 0, 0, 0);
            acc = __builtin_amdgcn_mfma_f32_16x16x32_bf16(qfrag[1], b1, acc, 0, 0, 0);
            const int col = k0 + keyl;
            const int* mp = Mb + (size_t)(qw + quad * 4) * S_LEN + col;
            float* ap = Abh + (size_t)(qw + quad * 4) * S_LEN + col;
            #pragma unroll
            for (int r = 0; r < 4; ++r) {
                int m = mp[(size_t)r * S_LEN];
                float p = m ? 0.f : exp2f(acc[r] * LOG2E);
                __builtin_nontemporal_store(p * inv_l[r], ap + (size_t)r * S_LEN);
                Pw[(quad * 4 + r) * 72 + keyl] = f2bs(p);  // unnormalized P for PV
            }
        }

        // PV: P is wave-private in LDS; in-wave ds ordering + compiler lgkmcnt suffice.
        #pragma unroll
        for (int kc = 0; kc < 2; ++kc) {
            bf16x8 af = *(const bf16x8*)&Pw[l16 * 72 + kc * 32 + quad * 8];
            #pragma unroll
            for (int dc = 0; dc < 4; ++dc) {
                bf16x8 bf = *(const bf16x8*)&Vt[(dc * 16 + l16) * 72 + kc * 32 + quad * 8];
                cacc[dc] = __builtin_amdgcn_mfma_f32_16x16x32_bf16(af, bf, cacc[dc], 0, 0, 0);
            }
        }
    }

    // epilogue: context = (P.V)/l
    #pragma unroll
    for (int dc = 0; dc < 4; ++dc) {
        #pragma unroll
        for (int r = 0; r < 4; ++r) {
            Cbh[(size_t)(qw + quad * 4 + r) * D_DIM + dc * 16 + l16] =
                cacc[dc][r] * inv_l[r];
        }
    }
}

extern "C" void kernel_launch(void* const* d_in, const int* in_sizes, int n_in,
                              void* d_out, int out_size, void* d_ws, size_t ws_size,
                              hipStream_t stream) {
    const float* Q    = (const float*)d_in[0];
    const float* K    = (const float*)d_in[1];
    const float* V    = (const float*)d_in[2];
    const int*   Mask = (const int*)d_in[3];   // bool -> int32 per harness convention
    // d_in[4] = dim_key = 64 (hardcoded)

    float* Ctx  = (float*)d_out;                                   // (2,16,2048,64)
    float* Attn = (float*)d_out + (size_t)2 * 16 * 2048 * 64;      // (2,16,2048,2048)

    sdpa_kernel<<<dim3(512), dim3(512), 0, stream>>>(Q, K, V, Mask, Ctx, Attn);
}

// Round 2
// 725.680 us; speedup vs baseline: 1.0484x; 1.0484x over previous
//
#include <hip/hip_runtime.h>
#include <hip/hip_bf16.h>

// SDPA, attention materialized. B=2 H=16 S=2048 D=64, fp32 in/out.
// Round 2: packed bitmask (ballot), bf16-preconverted K + transposed V in d_ws,
// global_load_lds(16B) staging with XOR-swizzled LDS, 256-thr wgs (4/CU),
// log2e folded into Q scale, native exp2.

#define S_LEN 2048
#define D_DIM 64
#define LOG2E 1.44269504088896340736f

typedef __attribute__((ext_vector_type(8))) short bf16x8;
typedef __attribute__((ext_vector_type(4))) float f32x4;
typedef unsigned long long u64;

__device__ __forceinline__ unsigned int f2bs2(float x, float y) {
    union { __hip_bfloat162 h; unsigned int u; } u;
    u.h = __float22bfloat162_rn(make_float2(x, y));
    return u.u;
}
__device__ __forceinline__ short f2bs(float f) {
    union { __hip_bfloat16 h; short s; } u;
    u.h = __float2bfloat16(f);
    return u.s;
}
__device__ __forceinline__ bf16x8 cvt8(float4 a, float4 b) {
    union { bf16x8 v; unsigned int w[4]; } u;
    u.w[0] = f2bs2(a.x, a.y); u.w[1] = f2bs2(a.z, a.w);
    u.w[2] = f2bs2(b.x, b.y); u.w[3] = f2bs2(b.z, b.w);
    return u.v;
}

__device__ __forceinline__ void gl2lds16(const short* g, short* l) {
    __builtin_amdgcn_global_load_lds(
        (const __attribute__((address_space(1))) unsigned int*)g,
        (__attribute__((address_space(3))) unsigned int*)l, 16, 0, 0);
}

// ---- prep: K,V fp32 -> bf16; V transposed to [bh][d][key] ----
__global__ __launch_bounds__(256) void prep_kv(const float* __restrict__ K,
                                               const float* __restrict__ V,
                                               short* __restrict__ Kb,
                                               short* __restrict__ Vtb) {
    __shared__ short T[64 * 80];
    const int bh = blockIdx.x >> 5;
    const int kt = blockIdx.x & 31;
    const int k0 = kt * 64;
    const int t  = threadIdx.x;
    const int row = t >> 2;          // key within tile
    const int cq  = (t & 3) * 16;    // d chunk

    const size_t base = (size_t)bh * S_LEN * D_DIM;
    {
        const float* kp = K + base + (size_t)(k0 + row) * D_DIM + cq;
        float4 a = ((const float4*)kp)[0], b = ((const float4*)kp)[1],
               c = ((const float4*)kp)[2], d = ((const float4*)kp)[3];
        short* op = Kb + base + (size_t)(k0 + row) * D_DIM + cq;
        *(bf16x8*)op       = cvt8(a, b);
        *(bf16x8*)(op + 8) = cvt8(c, d);
    }
    {
        const float* vp = V + base + (size_t)(k0 + row) * D_DIM + cq;
        float4 a = ((const float4*)vp)[0], b = ((const float4*)vp)[1],
               c = ((const float4*)vp)[2], d = ((const float4*)vp)[3];
        float vv[16] = {a.x,a.y,a.z,a.w, b.x,b.y,b.z,b.w,
                        c.x,c.y,c.z,c.w, d.x,d.y,d.z,d.w};
        #pragma unroll
        for (int i = 0; i < 16; ++i)
            T[(cq + i) * 80 + row] = f2bs(vv[i]);   // LDS transpose
    }
    __syncthreads();
    {
        const int d  = t >> 2;
        const int kc = (t & 3) * 16;
        short* op = Vtb + (size_t)bh * D_DIM * S_LEN + (size_t)d * S_LEN + k0 + kc;
        *(bf16x8*)op       = *(const bf16x8*)&T[d * 80 + kc];
        *(bf16x8*)(op + 8) = *(const bf16x8*)&T[d * 80 + kc + 8];
    }
}

// ---- mask -> 1 bit per col, u64 per 64 cols: Mp[(b*S+row)*32 + w] ----
__global__ __launch_bounds__(256) void mask_pack(const int* __restrict__ M,
                                                 u64* __restrict__ Mp) {
    const int lane = threadIdx.x & 63;
    const int wid  = (blockIdx.x * 256 + threadIdx.x) >> 6;
    const int nwaves = gridDim.x * 4;
    const int nwords = 2 * S_LEN * (S_LEN / 64);
    for (int w = wid; w < nwords; w += nwaves) {
        int v = M[(size_t)w * 64 + lane];
        u64 bits = __ballot(v != 0);
        if (lane == 0) Mp[w] = bits;
    }
}

// ---- main ----
__global__ __launch_bounds__(256, 4) void sdpa_main(
    const float* __restrict__ Q, const short* __restrict__ Kb,
    const short* __restrict__ Vtb, const u64* __restrict__ Mp,
    float* __restrict__ Ctx, float* __restrict__ Attn)
{
    // XOR-swizzled unpadded tiles (global_load_lds forces lane-contiguous dest):
    // element (row, chunk c of 8 shorts) lives at row*64 + (c^(row&7))*8.
    __shared__ short Kt[64 * 64];
    __shared__ short Vt[64 * 64];
    __shared__ short Pt[4 * 16 * 80];   // per-wave P round-trip, stride 80 (16B-aligned rows)

    const int tid  = threadIdx.x;
    const int wave = tid >> 6;
    const int lane = tid & 63;
    const int quad = lane >> 4;
    const int l16  = lane & 15;

    const int bid = blockIdx.x;                    // 1024 = 32 bh x 32 qt
    const int bh  = ((bid >> 8) << 3) | (bid & 7); // same-bh blocks share bid%8 (XCD L2)
    const int qt  = (bid >> 3) & 31;
    const int b   = bh >> 4;
    const int qw  = qt * 64 + wave * 16;

    const size_t sd_off = (size_t)bh * S_LEN * D_DIM;
    const float* Qbh = Q + sd_off;
    const short* Kbh = Kb + sd_off;                       // [key][d] bf16
    const short* Vbh = Vtb + (size_t)bh * D_DIM * S_LEN;  // [d][key] bf16
    float* Cbh = Ctx + sd_off;
    float* Abh = Attn + (size_t)bh * S_LEN * S_LEN;

    // Q A-frag; scale folds 1/sqrt(64) and log2e (exp(x)=exp2(x*log2e))
    bf16x8 qfrag[2];
    {
        const int qrow = qw + l16;
        const float s = 0.125f * LOG2E;
        #pragma unroll
        for (int kc = 0; kc < 2; ++kc) {
            const float* qp = Qbh + (size_t)qrow * D_DIM + kc * 32 + quad * 8;
            float4 a = ((const float4*)qp)[0], c = ((const float4*)qp)[1];
            a.x*=s; a.y*=s; a.z*=s; a.w*=s; c.x*=s; c.y*=s; c.z*=s; c.w*=s;
            qfrag[kc] = cvt8(a, c);
        }
    }

    const int mrow0 = (b * S_LEN + qw + quad * 4) * (S_LEN / 64);

    // ================= sweep 1: row sums =================
    float lacc[4] = {0.f, 0.f, 0.f, 0.f};
    for (int kt = 0; kt < 32; ++kt) {
        const int k0 = kt * 64;
        __syncthreads();
        #pragma unroll
        for (int rd = 0; rd < 2; ++rd) {
            const int m = tid + rd * 256;
            const int row = m >> 3, sc = m & 7, c = sc ^ (row & 7);
            gl2lds16(Kbh + (size_t)(k0 + row) * D_DIM + c * 8, &Kt[m * 8]);
        }
        __syncthreads();
        u64 mw[4];
        #pragma unroll
        for (int r = 0; r < 4; ++r) mw[r] = Mp[mrow0 + r * 32 + kt];
        #pragma unroll
        for (int cc = 0; cc < 4; ++cc) {
            const int keyl = cc * 16 + l16;
            f32x4 acc = {0.f, 0.f, 0.f, 0.f};
            #pragma unroll
            for (int kc = 0; kc < 2; ++kc) {
                bf16x8 bfr = *(const bf16x8*)&Kt[keyl * 64 + ((kc * 4 + quad) ^ (keyl & 7)) * 8];
                acc = __builtin_amdgcn_mfma_f32_16x16x32_bf16(qfrag[kc], bfr, acc, 0, 0, 0);
            }
            #pragma unroll
            for (int r = 0; r < 4; ++r) {
                float p = __builtin_amdgcn_exp2f(acc[r]);
                p = ((mw[r] >> keyl) & 1ull) ? 0.f : p;
                lacc[r] += p;
            }
        }
    }
    #pragma unroll
    for (int off = 1; off < 16; off <<= 1) {
        #pragma unroll
        for (int r = 0; r < 4; ++r) lacc[r] += __shfl_xor(lacc[r], off, 64);
    }
    float inv_l[4];
    #pragma unroll
    for (int r = 0; r < 4; ++r) inv_l[r] = 1.0f / lacc[r];

    // ================= sweep 2: attn write + PV =================
    f32x4 cacc[4];
    #pragma unroll
    for (int dc = 0; dc < 4; ++dc) cacc[dc] = (f32x4){0.f, 0.f, 0.f, 0.f};
    short* Pw = &Pt[wave * 16 * 80];

    for (int kt = 0; kt < 32; ++kt) {
        const int k0 = kt * 64;
        __syncthreads();
        #pragma unroll
        for (int rd = 0; rd < 2; ++rd) {
            const int m = tid + rd * 256;
            const int row = m >> 3, sc = m & 7, c = sc ^ (row & 7);
            gl2lds16(Kbh + (size_t)(k0 + row) * D_DIM + c * 8, &Kt[m * 8]);
            gl2lds16(Vbh + (size_t)row * S_LEN + k0 + c * 8, &Vt[m * 8]);
        }
        __syncthreads();
        u64 mw[4];
        #pragma unroll
        for (int r = 0; r < 4; ++r) mw[r] = Mp[mrow0 + r * 32 + kt];
        float* ap0 = Abh + (size_t)(qw + quad * 4) * S_LEN + k0;
        #pragma unroll
        for (int cc = 0; cc < 4; ++cc) {
            const int keyl = cc * 16 + l16;
            f32x4 acc = {0.f, 0.f, 0.f, 0.f};
            #pragma unroll
            for (int kc = 0; kc < 2; ++kc) {
                bf16x8 bfr = *(const bf16x8*)&Kt[keyl * 64 + ((kc * 4 + quad) ^ (keyl & 7)) * 8];
                acc = __builtin_amdgcn_mfma_f32_16x16x32_bf16(qfrag[kc], bfr, acc, 0, 0, 0);
            }
            #pragma unroll
            for (int r = 0; r < 4; ++r) {
                float p = __builtin_amdgcn_exp2f(acc[r]);
                p = ((mw[r] >> keyl) & 1ull) ? 0.f : p;
                __builtin_nontemporal_store(p * inv_l[r], ap0 + (size_t)r * S_LEN + keyl);
                Pw[(quad * 4 + r) * 80 + keyl] = f2bs(p);   // unnormalized P
            }
        }
        // PV: wave-private Pt, in-wave lgkmcnt ordering suffices
        #pragma unroll
        for (int kc = 0; kc < 2; ++kc) {
            bf16x8 af = *(const bf16x8*)&Pw[l16 * 80 + kc * 32 + quad * 8];
            #pragma unroll
            for (int dc = 0; dc < 4; ++dc) {
                const int vrow = dc * 16 + l16;
                bf16x8 bfr = *(const bf16x8*)&Vt[vrow * 64 + ((kc * 4 + quad) ^ (vrow & 7)) * 8];
                cacc[dc] = __builtin_amdgcn_mfma_f32_16x16x32_bf16(af, bfr, cacc[dc], 0, 0, 0);
            }
        }
    }

    #pragma unroll
    for (int dc = 0; dc < 4; ++dc) {
        #pragma unroll
        for (int r = 0; r < 4; ++r) {
            Cbh[(size_t)(qw + quad * 4 + r) * D_DIM + dc * 16 + l16] =
                cacc[dc][r] * inv_l[r];
        }
    }
}

extern "C" void kernel_launch(void* const* d_in, const int* in_sizes, int n_in,
                              void* d_out, int out_size, void* d_ws, size_t ws_size,
                              hipStream_t stream) {
    const float* Q    = (const float*)d_in[0];
    const float* K    = (const float*)d_in[1];
    const float* V    = (const float*)d_in[2];
    const int*   Mask = (const int*)d_in[3];

    float* Ctx  = (float*)d_out;
    float* Attn = (float*)d_out + (size_t)2 * 16 * 2048 * 64;

    short* Kb  = (short*)d_ws;                           // 8,388,608 B
    short* Vtb = (short*)((char*)d_ws + 8388608);        // 8,388,608 B
    u64*   Mp  = (u64*)((char*)d_ws + 16777216);         // 1,048,576 B

    prep_kv<<<dim3(1024), dim3(256), 0, stream>>>(K, V, Kb, Vtb);
    mask_pack<<<dim3(512), dim3(256), 0, stream>>>(Mask, Mp);
    sdpa_main<<<dim3(1024), dim3(256), 0, stream>>>(Q, Kb, Vtb, Mp, Ctx, Attn);
}